// Round 1
// baseline (5428.512 us; speedup 1.0000x reference)
//
#include <hip/hip_runtime.h>
#include <math.h>
#include <limits.h>

// ---- problem constants ----
#define C_IN 256
#define HM_H 136
#define HM_W 240
#define HM_N (HM_H * HM_W)      // 32640
#define MB   64                 // mask-branch channels
#define MH   272
#define MW   480
#define MN   (MH * MW)          // 130560
#define NP   134                // NUM_GEN_PARAMS
#define NI   4                  // num_ins
#define HID  64

// d_out layout (floats): scores[4] | inds[4] | regs0[4*MN] | masks0[4*MN] | feat[4*480*2]
#define REG_OFF   8
#define MASK_OFF  (8 + NI * MN)
#define FEAT_OFF  (8 + 2 * NI * MN)

// workspace layout (floats): hm[HM_N] | nms[HM_N] | gp[NI*NP] | inds(int)[NI]

// ------------------------------------------------------------------
// K1: hm = clip(sigmoid(hm_w . out1 + hm_b))
// ------------------------------------------------------------------
__global__ void k_hm(const float* __restrict__ out1, const float* __restrict__ hm_w,
                     const float* __restrict__ hm_b, float* __restrict__ ws_hm) {
  int p = blockIdx.x * 256 + threadIdx.x;
  if (p >= HM_N) return;
  float s = 0.f;
  #pragma unroll 8
  for (int c = 0; c < C_IN; ++c) s += hm_w[c] * out1[c * HM_N + p];
  s += hm_b[0];
  float sig = 1.f / (1.f + expf(-s));
  sig = fminf(fmaxf(sig, 1e-4f), 1.f - 1e-4f);
  ws_hm[p] = sig;
}

// ------------------------------------------------------------------
// K2a: 3x3 NMS (keep where value == window max; -inf padding == skip OOB)
// ------------------------------------------------------------------
__global__ void k_nms(const float* __restrict__ ws_hm, float* __restrict__ ws_nms) {
  int p = blockIdx.x * 256 + threadIdx.x;
  if (p >= HM_N) return;
  int y = p / HM_W, x = p - y * HM_W;
  float c = ws_hm[p];
  float m = c;
  #pragma unroll
  for (int dy = -1; dy <= 1; ++dy) {
    #pragma unroll
    for (int dx = -1; dx <= 1; ++dx) {
      int yy = y + dy, xx = x + dx;
      if (yy >= 0 && yy < HM_H && xx >= 0 && xx < HM_W)
        m = fmaxf(m, ws_hm[yy * HM_W + xx]);
    }
  }
  ws_nms[p] = (c == m) ? c : 0.f;
}

// ------------------------------------------------------------------
// K2b: top-4 over 32640 (single block, 1024 threads). Tie-break: lower index.
// Writes scores -> d_out[0..3], float(inds) -> d_out[4..7], inds -> ws_inds.
// ------------------------------------------------------------------
__device__ __forceinline__ bool better(float av, int ai, float bv, int bi) {
  return (av > bv) || (av == bv && ai < bi);
}

__global__ void k_topk(const float* __restrict__ ws_nms, int* __restrict__ ws_inds,
                       float* __restrict__ d_out) {
  __shared__ float sv[1024 * 4];
  __shared__ int   si[1024 * 4];
  int t = threadIdx.x;
  float bv[4] = {-1.f, -1.f, -1.f, -1.f};
  int   bi[4] = {INT_MAX, INT_MAX, INT_MAX, INT_MAX};
  for (int p = t; p < HM_N; p += 1024) {
    float v = ws_nms[p];
    if (better(v, p, bv[3], bi[3])) {
      bv[3] = v; bi[3] = p;
      #pragma unroll
      for (int k = 3; k > 0; --k) {
        if (better(bv[k], bi[k], bv[k - 1], bi[k - 1])) {
          float tv = bv[k]; bv[k] = bv[k - 1]; bv[k - 1] = tv;
          int   ti = bi[k]; bi[k] = bi[k - 1]; bi[k - 1] = ti;
        }
      }
    }
  }
  #pragma unroll
  for (int k = 0; k < 4; ++k) { sv[t * 4 + k] = bv[k]; si[t * 4 + k] = bi[k]; }
  __syncthreads();
  for (int s = 512; s >= 1; s >>= 1) {
    if (t < s) {
      float a[4], b[4]; int ai[4], bj[4];
      #pragma unroll
      for (int k = 0; k < 4; ++k) {
        a[k] = sv[t * 4 + k];        ai[k] = si[t * 4 + k];
        b[k] = sv[(t + s) * 4 + k];  bj[k] = si[(t + s) * 4 + k];
      }
      float ov[4]; int oi[4];
      int i = 0, j = 0;
      #pragma unroll
      for (int k = 0; k < 4; ++k) {
        if (better(a[i], ai[i], b[j], bj[j])) { ov[k] = a[i]; oi[k] = ai[i]; ++i; }
        else                                   { ov[k] = b[j]; oi[k] = bj[j]; ++j; }
      }
      #pragma unroll
      for (int k = 0; k < 4; ++k) { sv[t * 4 + k] = ov[k]; si[t * 4 + k] = oi[k]; }
    }
    __syncthreads();
  }
  if (t == 0) {
    #pragma unroll
    for (int k = 0; k < 4; ++k) {
      d_out[k]     = sv[k];
      d_out[4 + k] = (float)si[k];
      ws_inds[k]   = si[k];
    }
  }
}

// ------------------------------------------------------------------
// K3: gen_params for the 4 winners: gp[i][j] = params_b[j] + params_w[j,:] . out1[:,p_i]
// ------------------------------------------------------------------
__global__ void k_gen(const float* __restrict__ out1, const float* __restrict__ params_w,
                      const float* __restrict__ params_b, const int* __restrict__ ws_inds,
                      float* __restrict__ ws_gp) {
  __shared__ float col[C_IN];
  int i = blockIdx.x;
  int p = ws_inds[i];
  col[threadIdx.x] = out1[threadIdx.x * HM_N + p];
  __syncthreads();
  int j = threadIdx.x;
  if (j < NP) {
    float s = params_b[j];
    #pragma unroll 8
    for (int c = 0; c < C_IN; ++c) s += params_w[j * C_IN + c] * col[c];
    ws_gp[i * NP + j] = s;
  }
}

// ------------------------------------------------------------------
// K4: fused 3x3 conv (256->64) + bias + relu + dynamic heads.
// Thread-per-pixel, 64 fp32 accumulators; weights via wave-uniform (scalar) loads.
// ------------------------------------------------------------------
#define TW 32
#define TH 8
#define CC 4

__global__ __launch_bounds__(256, 2) void k_conv_head(
    const float* __restrict__ out0, const float* __restrict__ mb_w,
    const float* __restrict__ mb_b, const float* __restrict__ ws_gp,
    float* __restrict__ d_out) {
  __shared__ float sm[CC][TH + 2][TW + 2];
  int tid = threadIdx.x;
  int tx = tid & 31, ty = tid >> 5;
  int bx = blockIdx.x, by = blockIdx.y;
  int gx = bx * TW + tx, gy = by * TH + ty;

  float acc[MB];
  #pragma unroll
  for (int o = 0; o < MB; ++o) acc[o] = 0.f;

  #pragma unroll 1
  for (int c0 = 0; c0 < C_IN; c0 += CC) {
    __syncthreads();
    for (int idx = tid; idx < CC * (TH + 2) * (TW + 2); idx += 256) {
      int cc  = idx / ((TH + 2) * (TW + 2));
      int rem = idx - cc * ((TH + 2) * (TW + 2));
      int yy  = rem / (TW + 2);
      int xx  = rem - yy * (TW + 2);
      int iy = by * TH + yy - 1, ix = bx * TW + xx - 1;
      float v = 0.f;
      if (iy >= 0 && iy < MH && ix >= 0 && ix < MW)
        v = out0[(c0 + cc) * MN + iy * MW + ix];
      sm[cc][yy][xx] = v;
    }
    __syncthreads();
    #pragma unroll
    for (int cc = 0; cc < CC; ++cc) {
      float p0 = sm[cc][ty + 0][tx + 0], p1 = sm[cc][ty + 0][tx + 1], p2 = sm[cc][ty + 0][tx + 2];
      float p3 = sm[cc][ty + 1][tx + 0], p4 = sm[cc][ty + 1][tx + 1], p5 = sm[cc][ty + 1][tx + 2];
      float p6 = sm[cc][ty + 2][tx + 0], p7 = sm[cc][ty + 2][tx + 1], p8 = sm[cc][ty + 2][tx + 2];
      const float* w = mb_w + (c0 + cc) * 9;   // mb_w[o][c][tap] at o*2304 + c*9 + tap
      #pragma unroll
      for (int o = 0; o < MB; ++o) {
        const float* w9 = w + o * 2304;        // wave-uniform -> s_load
        acc[o] += w9[0] * p0 + w9[1] * p1 + w9[2] * p2
                + w9[3] * p3 + w9[4] * p4 + w9[5] * p5
                + w9[6] * p6 + w9[7] * p7 + w9[8] * p8;
      }
    }
  }

  #pragma unroll
  for (int o = 0; o < MB; ++o) acc[o] = fmaxf(acc[o] + mb_b[o], 0.f);

  float xc = -1.f + (2.f / 479.f) * (float)gx;
  float yc = -1.f + (2.f / 271.f) * (float)gy;
  int pix = gy * MW + gx;
  #pragma unroll
  for (int i = 0; i < NI; ++i) {
    const float* g = ws_gp + i * NP;           // wave-uniform -> s_load
    float m = g[66]  + g[64]  * xc + g[65]  * yc;
    float r = g[133] + g[131] * xc + g[132] * yc;
    #pragma unroll
    for (int o = 0; o < MB; ++o) {
      m += g[o] * acc[o];
      r += g[67 + o] * acc[o];
    }
    d_out[REG_OFF  + i * MN + pix] = r;
    d_out[MASK_OFF + i * MN + pix] = m;
  }
}

// ------------------------------------------------------------------
// K5: feat_range MLP. block = (i, w) pair; 64 threads (one per hidden unit).
// ------------------------------------------------------------------
__global__ void k_mlp(const float* __restrict__ masks0, const float* __restrict__ w1,
                      const float* __restrict__ b1, const float* __restrict__ w2,
                      const float* __restrict__ b2, float* __restrict__ d_out) {
  int blk = blockIdx.x;          // i*480 + w
  int i = blk / MW;
  int w = blk - i * MW;
  int k = threadIdx.x;           // 0..63
  const float* mcol = masks0 + i * MN + w;  // masks0[i, h, w], stride MW over h
  float s = b1[k];
  for (int h = 0; h < MH; ++h) s += mcol[h * MW] * w1[h * HID + k];
  s = fmaxf(s, 0.f);
  float o0 = s * w2[k * 2 + 0];
  float o1 = s * w2[k * 2 + 1];
  #pragma unroll
  for (int off = 32; off >= 1; off >>= 1) {
    o0 += __shfl_down(o0, off);
    o1 += __shfl_down(o1, off);
  }
  if (k == 0) {
    d_out[FEAT_OFF + blk * 2 + 0] = o0 + b2[0];
    d_out[FEAT_OFF + blk * 2 + 1] = o1 + b2[1];
  }
}

// ------------------------------------------------------------------
extern "C" void kernel_launch(void* const* d_in, const int* in_sizes, int n_in,
                              void* d_out, int out_size, void* d_ws, size_t ws_size,
                              hipStream_t stream) {
  const float* out0     = (const float*)d_in[0];
  const float* out1     = (const float*)d_in[1];
  const float* hm_w     = (const float*)d_in[2];
  const float* hm_b     = (const float*)d_in[3];
  const float* params_w = (const float*)d_in[4];
  const float* params_b = (const float*)d_in[5];
  const float* mb_w     = (const float*)d_in[6];
  const float* mb_b     = (const float*)d_in[7];
  const float* mlp_w1   = (const float*)d_in[8];
  const float* mlp_b1   = (const float*)d_in[9];
  const float* mlp_w2   = (const float*)d_in[10];
  const float* mlp_b2   = (const float*)d_in[11];

  float* ws      = (float*)d_ws;
  float* ws_hm   = ws;
  float* ws_nms  = ws + HM_N;
  float* ws_gp   = ws + 2 * HM_N;
  int*   ws_inds = (int*)(ws + 2 * HM_N + NI * NP);
  float* out     = (float*)d_out;

  k_hm  <<<(HM_N + 255) / 256, 256, 0, stream>>>(out1, hm_w, hm_b, ws_hm);
  k_nms <<<(HM_N + 255) / 256, 256, 0, stream>>>(ws_hm, ws_nms);
  k_topk<<<1, 1024, 0, stream>>>(ws_nms, ws_inds, out);
  k_gen <<<NI, 256, 0, stream>>>(out1, params_w, params_b, ws_inds, ws_gp);
  dim3 gconv(MW / TW, MH / TH);   // 15 x 34
  k_conv_head<<<gconv, 256, 0, stream>>>(out0, mb_w, mb_b, ws_gp, out);
  k_mlp <<<NI * MW, 64, 0, stream>>>(out + MASK_OFF, mlp_w1, mlp_b1, mlp_w2, mlp_b2, out);
}

// Round 2
// 479.790 us; speedup vs baseline: 11.3143x; 11.3143x over previous
//
#include <hip/hip_runtime.h>
#include <math.h>
#include <limits.h>

// ---- problem constants ----
#define C_IN 256
#define HM_H 136
#define HM_W 240
#define HM_N (HM_H * HM_W)      // 32640
#define MB   64                 // mask-branch channels
#define MH   272
#define MW   480
#define MN   (MH * MW)          // 130560
#define NP   134                // NUM_GEN_PARAMS
#define NI   4                  // num_ins
#define HID  64

// d_out layout (floats): scores[4] | inds[4] | regs0[4*MN] | masks0[4*MN] | feat[4*480*2]
#define REG_OFF   8
#define MASK_OFF  (8 + NI * MN)
#define FEAT_OFF  (8 + 2 * NI * MN)

// ws layout (floats): hm[32640] | nms[32640] | gp[536] | inds(int)[4] | pad | wt(ushort[147456]) @ float ofs 65824
#define WS_HM   0
#define WS_NMS  HM_N
#define WS_GP   (2 * HM_N)
#define WS_INDS (2 * HM_N + NI * NP)
#define WS_WT_F 65824            // float offset, 16B aligned

typedef float  f32x4  __attribute__((ext_vector_type(4)));
typedef short  bf16x8 __attribute__((ext_vector_type(8)));

__device__ __forceinline__ unsigned short f2bf(float f) {
  unsigned int u = __float_as_uint(f);
  u += 0x7FFFu + ((u >> 16) & 1u);       // RNE
  return (unsigned short)(u >> 16);
}
__device__ __forceinline__ float b2f(unsigned short h) {
  return __uint_as_float(((unsigned int)h) << 16);
}

// ------------------------------------------------------------------
// K0: weight prep — swizzle mb_w (OIHW fp32) into bf16 MFMA B-fragment order:
// wt[(((g*9+t)*4+nt)*64+lane)*8+j] = bf16( mb_w[(n*256+c)*9+t] ),
//   n = nt*16 + (lane&15), c = g*32 + (lane>>4)*8 + j
// ------------------------------------------------------------------
__global__ void k_wprep(const float* __restrict__ mb_w, unsigned short* __restrict__ wt) {
  int idx = blockIdx.x * 256 + threadIdx.x;     // 147456 total
  int j    = idx & 7;
  int lane = (idx >> 3) & 63;
  int nt   = (idx >> 9) & 3;
  int gt   = idx >> 11;                          // g*9 + t
  int t    = gt % 9;
  int g    = gt / 9;
  int n = nt * 16 + (lane & 15);
  int c = g * 32 + (lane >> 4) * 8 + j;
  wt[idx] = f2bf(mb_w[(n * C_IN + c) * 9 + t]);
}

// ------------------------------------------------------------------
// K1: hm = clip(sigmoid(hm_w . out1 + hm_b))
// ------------------------------------------------------------------
__global__ void k_hm(const float* __restrict__ out1, const float* __restrict__ hm_w,
                     const float* __restrict__ hm_b, float* __restrict__ ws_hm) {
  int p = blockIdx.x * 256 + threadIdx.x;
  if (p >= HM_N) return;
  float s = 0.f;
  #pragma unroll 8
  for (int c = 0; c < C_IN; ++c) s += hm_w[c] * out1[c * HM_N + p];
  s += hm_b[0];
  float sig = 1.f / (1.f + expf(-s));
  sig = fminf(fmaxf(sig, 1e-4f), 1.f - 1e-4f);
  ws_hm[p] = sig;
}

// ------------------------------------------------------------------
// K2a: 3x3 NMS
// ------------------------------------------------------------------
__global__ void k_nms(const float* __restrict__ ws_hm, float* __restrict__ ws_nms) {
  int p = blockIdx.x * 256 + threadIdx.x;
  if (p >= HM_N) return;
  int y = p / HM_W, x = p - y * HM_W;
  float c = ws_hm[p];
  float m = c;
  #pragma unroll
  for (int dy = -1; dy <= 1; ++dy) {
    #pragma unroll
    for (int dx = -1; dx <= 1; ++dx) {
      int yy = y + dy, xx = x + dx;
      if (yy >= 0 && yy < HM_H && xx >= 0 && xx < HM_W)
        m = fmaxf(m, ws_hm[yy * HM_W + xx]);
    }
  }
  ws_nms[p] = (c == m) ? c : 0.f;
}

// ------------------------------------------------------------------
// K2b: top-4 over 32640 (single block, 1024 threads). Tie-break: lower index.
// ------------------------------------------------------------------
__device__ __forceinline__ bool better(float av, int ai, float bv, int bi) {
  return (av > bv) || (av == bv && ai < bi);
}

__global__ void k_topk(const float* __restrict__ ws_nms, int* __restrict__ ws_inds,
                       float* __restrict__ d_out) {
  __shared__ float sv[1024 * 4];
  __shared__ int   si[1024 * 4];
  int t = threadIdx.x;
  float bv[4] = {-1.f, -1.f, -1.f, -1.f};
  int   bi[4] = {INT_MAX, INT_MAX, INT_MAX, INT_MAX};
  for (int p = t; p < HM_N; p += 1024) {
    float v = ws_nms[p];
    if (better(v, p, bv[3], bi[3])) {
      bv[3] = v; bi[3] = p;
      #pragma unroll
      for (int k = 3; k > 0; --k) {
        if (better(bv[k], bi[k], bv[k - 1], bi[k - 1])) {
          float tv = bv[k]; bv[k] = bv[k - 1]; bv[k - 1] = tv;
          int   ti = bi[k]; bi[k] = bi[k - 1]; bi[k - 1] = ti;
        }
      }
    }
  }
  #pragma unroll
  for (int k = 0; k < 4; ++k) { sv[t * 4 + k] = bv[k]; si[t * 4 + k] = bi[k]; }
  __syncthreads();
  for (int s = 512; s >= 1; s >>= 1) {
    if (t < s) {
      float a[4], b[4]; int ai[4], bj[4];
      #pragma unroll
      for (int k = 0; k < 4; ++k) {
        a[k] = sv[t * 4 + k];        ai[k] = si[t * 4 + k];
        b[k] = sv[(t + s) * 4 + k];  bj[k] = si[(t + s) * 4 + k];
      }
      float ov[4]; int oi[4];
      int i = 0, j = 0;
      #pragma unroll
      for (int k = 0; k < 4; ++k) {
        if (better(a[i], ai[i], b[j], bj[j])) { ov[k] = a[i]; oi[k] = ai[i]; ++i; }
        else                                   { ov[k] = b[j]; oi[k] = bj[j]; ++j; }
      }
      #pragma unroll
      for (int k = 0; k < 4; ++k) { sv[t * 4 + k] = ov[k]; si[t * 4 + k] = oi[k]; }
    }
    __syncthreads();
  }
  if (t == 0) {
    #pragma unroll
    for (int k = 0; k < 4; ++k) {
      d_out[k]     = sv[k];
      d_out[4 + k] = (float)si[k];
      ws_inds[k]   = si[k];
    }
  }
}

// ------------------------------------------------------------------
// K3: gen_params for the 4 winners
// ------------------------------------------------------------------
__global__ void k_gen(const float* __restrict__ out1, const float* __restrict__ params_w,
                      const float* __restrict__ params_b, const int* __restrict__ ws_inds,
                      float* __restrict__ ws_gp) {
  __shared__ float col[C_IN];
  int i = blockIdx.x;
  int p = ws_inds[i];
  col[threadIdx.x] = out1[threadIdx.x * HM_N + p];
  __syncthreads();
  int j = threadIdx.x;
  if (j < NP) {
    float s = params_b[j];
    #pragma unroll 8
    for (int c = 0; c < C_IN; ++c) s += params_w[j * C_IN + c] * col[c];
    ws_gp[i * NP + j] = s;
  }
}

// ------------------------------------------------------------------
// K4: MFMA implicit-GEMM 3x3 conv (256->64) + bias + relu + dynamic heads.
// Block = 8 rows x 32 cols = 256 pixels, 4 waves.
// K = 9 taps x 8 ch-groups of 32; mfma_f32_16x16x32_bf16.
// ------------------------------------------------------------------
#define CS 40      // staging LDS channel stride (ushorts): 80B -> 16B-aligned b128 reads
#define ES 66      // epilogue LDS stride (ushorts): conflict-free scalar reads

__global__ __launch_bounds__(256) void k_conv_mfma(
    const float* __restrict__ out0, const unsigned short* __restrict__ wt,
    const float* __restrict__ mb_b, const float* __restrict__ ws_gp,
    float* __restrict__ d_out) {
  __shared__ unsigned short smem[256 * ES];   // 33792 B; staging needs 10*34*40=13600

  int tid  = threadIdx.x;
  int lane = tid & 63;
  int w    = tid >> 6;         // wave 0..3
  int n15  = lane & 15;
  int kq   = lane >> 4;        // 0..3
  int bx = blockIdx.x, by = blockIdx.y;
  int gx0 = bx * 32, gy0 = by * 8;

  // per-thread A-frag geometry for the wave's 4 m-tiles
  int rrow[4], xbas[4];
  #pragma unroll
  for (int i = 0; i < 4; ++i) {
    int mt = w * 4 + i;
    rrow[i] = mt >> 1;
    xbas[i] = (mt & 1) * 16 + n15;
  }

  f32x4 acc[4][4];
  #pragma unroll
  for (int i = 0; i < 4; ++i)
    #pragma unroll
    for (int nt = 0; nt < 4; ++nt)
      acc[i][nt] = (f32x4){0.f, 0.f, 0.f, 0.f};

  #pragma unroll 1
  for (int g = 0; g < 8; ++g) {
    __syncthreads();
    // stage input tile [10 rows][34 x][32 c] (bf16) for ch-group g
    for (int idx = tid; idx < 10880; idx += 256) {
      int c   = idx / 340;
      int rem = idx - c * 340;
      int row = rem / 34;
      int x   = rem - row * 34;
      int iy = gy0 + row - 1, ix = gx0 + x - 1;
      float v = 0.f;
      if (iy >= 0 && iy < MH && ix >= 0 && ix < MW)
        v = out0[(g * 32 + c) * MN + iy * MW + ix];
      smem[(row * 34 + x) * CS + c] = f2bf(v);
    }
    __syncthreads();

    #pragma unroll 1
    for (int t = 0; t < 9; ++t) {
      int ty = t / 3, tx = t - ty * 3;   // 0..2 (the +1 halo offset is built in)
      const unsigned short* wb = wt + ((g * 9 + t) * 256 + lane) * 8;
      bf16x8 bfrag[4];
      #pragma unroll
      for (int nt = 0; nt < 4; ++nt)
        bfrag[nt] = *(const bf16x8*)(wb + nt * 512);
      bf16x8 afrag[4];
      #pragma unroll
      for (int i = 0; i < 4; ++i)
        afrag[i] = *(const bf16x8*)&smem[((rrow[i] + ty) * 34 + xbas[i] + tx) * CS + kq * 8];
      #pragma unroll
      for (int i = 0; i < 4; ++i)
        #pragma unroll
        for (int nt = 0; nt < 4; ++nt)
          acc[i][nt] = __builtin_amdgcn_mfma_f32_16x16x32_bf16(afrag[i], bfrag[nt], acc[i][nt], 0, 0, 0);
    }
  }

  // bias + relu, accumulators -> epilogue LDS [pixel][channel] (bf16)
  float bias[4];
  #pragma unroll
  for (int nt = 0; nt < 4; ++nt) bias[nt] = mb_b[nt * 16 + n15];
  __syncthreads();
  #pragma unroll
  for (int i = 0; i < 4; ++i) {
    int mt = w * 4 + i;
    int pbase = (mt >> 1) * 32 + (mt & 1) * 16;
    #pragma unroll
    for (int nt = 0; nt < 4; ++nt)
      #pragma unroll
      for (int reg = 0; reg < 4; ++reg) {
        float vv = fmaxf(acc[i][nt][reg] + bias[nt], 0.f);
        smem[(pbase + kq * 4 + reg) * ES + nt * 16 + n15] = f2bf(vv);
      }
  }
  __syncthreads();

  // dynamic heads: thread tid owns pixel tid
  int r = tid >> 5, xcol = tid & 31;
  int gy = gy0 + r, gx = gx0 + xcol;
  float xc = -1.f + (2.f / 479.f) * (float)gx;
  float yc = -1.f + (2.f / 271.f) * (float)gy;
  float mres[4] = {0.f, 0.f, 0.f, 0.f};
  float rres[4] = {0.f, 0.f, 0.f, 0.f};
  #pragma unroll 8
  for (int o = 0; o < MB; ++o) {
    float v = b2f(smem[tid * ES + o]);
    #pragma unroll
    for (int i = 0; i < 4; ++i) {
      mres[i] += ws_gp[i * NP + o] * v;
      rres[i] += ws_gp[i * NP + 67 + o] * v;
    }
  }
  int pix = gy * MW + gx;
  #pragma unroll
  for (int i = 0; i < 4; ++i) {
    const float* g = ws_gp + i * NP;
    d_out[MASK_OFF + i * MN + pix] = mres[i] + g[66]  + g[64]  * xc + g[65]  * yc;
    d_out[REG_OFF  + i * MN + pix] = rres[i] + g[133] + g[131] * xc + g[132] * yc;
  }
}

// ------------------------------------------------------------------
// K5: feat_range MLP
// ------------------------------------------------------------------
__global__ void k_mlp(const float* __restrict__ masks0, const float* __restrict__ w1,
                      const float* __restrict__ b1, const float* __restrict__ w2,
                      const float* __restrict__ b2, float* __restrict__ d_out) {
  int blk = blockIdx.x;          // i*480 + w
  int i = blk / MW;
  int w = blk - i * MW;
  int k = threadIdx.x;           // 0..63
  const float* mcol = masks0 + i * MN + w;
  float s = b1[k];
  for (int h = 0; h < MH; ++h) s += mcol[h * MW] * w1[h * HID + k];
  s = fmaxf(s, 0.f);
  float o0 = s * w2[k * 2 + 0];
  float o1 = s * w2[k * 2 + 1];
  #pragma unroll
  for (int off = 32; off >= 1; off >>= 1) {
    o0 += __shfl_down(o0, off);
    o1 += __shfl_down(o1, off);
  }
  if (k == 0) {
    d_out[FEAT_OFF + blk * 2 + 0] = o0 + b2[0];
    d_out[FEAT_OFF + blk * 2 + 1] = o1 + b2[1];
  }
}

// ------------------------------------------------------------------
extern "C" void kernel_launch(void* const* d_in, const int* in_sizes, int n_in,
                              void* d_out, int out_size, void* d_ws, size_t ws_size,
                              hipStream_t stream) {
  const float* out0     = (const float*)d_in[0];
  const float* out1     = (const float*)d_in[1];
  const float* hm_w     = (const float*)d_in[2];
  const float* hm_b     = (const float*)d_in[3];
  const float* params_w = (const float*)d_in[4];
  const float* params_b = (const float*)d_in[5];
  const float* mb_w     = (const float*)d_in[6];
  const float* mb_b     = (const float*)d_in[7];
  const float* mlp_w1   = (const float*)d_in[8];
  const float* mlp_b1   = (const float*)d_in[9];
  const float* mlp_w2   = (const float*)d_in[10];
  const float* mlp_b2   = (const float*)d_in[11];

  float* ws      = (float*)d_ws;
  float* ws_hm   = ws + WS_HM;
  float* ws_nms  = ws + WS_NMS;
  float* ws_gp   = ws + WS_GP;
  int*   ws_inds = (int*)(ws + WS_INDS);
  unsigned short* ws_wt = (unsigned short*)(ws + WS_WT_F);
  float* out     = (float*)d_out;

  k_wprep<<<576, 256, 0, stream>>>(mb_w, ws_wt);
  k_hm  <<<(HM_N + 255) / 256, 256, 0, stream>>>(out1, hm_w, hm_b, ws_hm);
  k_nms <<<(HM_N + 255) / 256, 256, 0, stream>>>(ws_hm, ws_nms);
  k_topk<<<1, 1024, 0, stream>>>(ws_nms, ws_inds, out);
  k_gen <<<NI, 256, 0, stream>>>(out1, params_w, params_b, ws_inds, ws_gp);
  dim3 gconv(MW / 32, MH / 8);   // 15 x 34
  k_conv_mfma<<<gconv, 256, 0, stream>>>(out0, ws_wt, mb_b, ws_gp, out);
  k_mlp <<<NI * MW, 64, 0, stream>>>(out + MASK_OFF, mlp_w1, mlp_b1, mlp_w2, mlp_b2, out);
}

// Round 3
// 356.914 us; speedup vs baseline: 15.2096x; 1.3443x over previous
//
#include <hip/hip_runtime.h>
#include <math.h>
#include <limits.h>

// ---- problem constants ----
#define C_IN 256
#define HM_H 136
#define HM_W 240
#define HM_N (HM_H * HM_W)      // 32640
#define MB   64
#define MH   272
#define MW   480
#define MN   (MH * MW)          // 130560
#define NP   134
#define NI   4
#define HID  64

// d_out layout (floats): scores[4] | inds[4] | regs0[4*MN] | masks0[4*MN] | feat[4*480*2]
#define REG_OFF   8
#define MASK_OFF  (8 + NI * MN)
#define FEAT_OFF  (8 + 2 * NI * MN)

// ws layout (floats): hm[32640] | cand_v[512]+cand_i[512] | gp[536] | inds(int)[4] | wt @ 65824
#define WS_HM   0
#define WS_CV   HM_N
#define WS_CI   (HM_N + 512)
#define WS_GP   (2 * HM_N)
#define WS_INDS (2 * HM_N + NI * NP)
#define WS_WT_F 65824

typedef float  f32x4  __attribute__((ext_vector_type(4)));
typedef short  bf16x8 __attribute__((ext_vector_type(8)));

__device__ __forceinline__ unsigned short f2bf(float f) {
  unsigned int u = __float_as_uint(f);
  u += 0x7FFFu + ((u >> 16) & 1u);
  return (unsigned short)(u >> 16);
}
__device__ __forceinline__ float b2f(unsigned short h) {
  return __uint_as_float(((unsigned int)h) << 16);
}

// ------------------------------------------------------------------
// K0: weight prep — swizzle mb_w (OIHW fp32) into bf16 MFMA B-fragment order.
// ------------------------------------------------------------------
__global__ void k_wprep(const float* __restrict__ mb_w, unsigned short* __restrict__ wt) {
  int idx = blockIdx.x * 256 + threadIdx.x;     // 147456 total
  int j    = idx & 7;
  int lane = (idx >> 3) & 63;
  int nt   = (idx >> 9) & 3;
  int gt   = idx >> 11;
  int t    = gt % 9;
  int g    = gt / 9;
  int n = nt * 16 + (lane & 15);
  int c = g * 32 + (lane >> 4) * 8 + j;
  wt[idx] = f2bf(mb_w[(n * C_IN + c) * 9 + t]);
}

// ------------------------------------------------------------------
// K1: hm = clip(sigmoid(hm_w . out1 + hm_b)); block = 64 pixels x 4 c-groups
// ------------------------------------------------------------------
__global__ void k_hm(const float* __restrict__ out1, const float* __restrict__ hm_w,
                     const float* __restrict__ hm_b, float* __restrict__ ws_hm) {
  __shared__ float part[4][64];
  int b = blockIdx.x, t = threadIdx.x;
  int cg = t >> 6, pl = t & 63;
  int p = b * 64 + pl;                         // 510*64 = 32640
  float s = 0.f;
  #pragma unroll 16
  for (int c = 0; c < 64; ++c)
    s += hm_w[cg * 64 + c] * out1[(cg * 64 + c) * HM_N + p];
  part[cg][pl] = s;
  __syncthreads();
  if (t < 64) {
    float tot = part[0][t] + part[1][t] + part[2][t] + part[3][t] + hm_b[0];
    float sig = 1.f / (1.f + expf(-tot));
    sig = fminf(fmaxf(sig, 1e-4f), 1.f - 1e-4f);
    ws_hm[b * 64 + t] = sig;
  }
}

// ------------------------------------------------------------------
// top-4 list merge helpers
// ------------------------------------------------------------------
__device__ __forceinline__ bool better(float av, int ai, float bv, int bi) {
  return (av > bv) || (av == bv && ai < bi);
}

// tree-merge top4 lists held in LDS (nthr entries of 4), result at entry 0
template<int NTHR>
__device__ void top4_tree(float* sv, int* si, int t) {
  for (int s = NTHR / 2; s >= 1; s >>= 1) {
    if (t < s) {
      float a[4], b[4]; int ai[4], bj[4];
      #pragma unroll
      for (int k = 0; k < 4; ++k) {
        a[k] = sv[t * 4 + k];        ai[k] = si[t * 4 + k];
        b[k] = sv[(t + s) * 4 + k];  bj[k] = si[(t + s) * 4 + k];
      }
      float ov[4]; int oi[4];
      int i = 0, j = 0;
      #pragma unroll
      for (int k = 0; k < 4; ++k) {
        if (better(a[i], ai[i], b[j], bj[j])) { ov[k] = a[i]; oi[k] = ai[i]; ++i; }
        else                                   { ov[k] = b[j]; oi[k] = bj[j]; ++j; }
      }
      #pragma unroll
      for (int k = 0; k < 4; ++k) { sv[t * 4 + k] = ov[k]; si[t * 4 + k] = oi[k]; }
    }
    __syncthreads();
  }
}

// ------------------------------------------------------------------
// K2a: fused NMS + per-block top-4 (128 blocks x 255 pixels)
// ------------------------------------------------------------------
__global__ void k_nms_top(const float* __restrict__ ws_hm, float* __restrict__ candv,
                          int* __restrict__ candi) {
  __shared__ float sv[256 * 4];
  __shared__ int   si[256 * 4];
  int b = blockIdx.x, t = threadIdx.x;
  float v = -1.f; int idx = INT_MAX;
  if (t < 255) {
    int p = b * 255 + t;
    int y = p / HM_W, x = p - y * HM_W;
    float c = ws_hm[p], m = c;
    #pragma unroll
    for (int dy = -1; dy <= 1; ++dy)
      #pragma unroll
      for (int dx = -1; dx <= 1; ++dx) {
        int yy = y + dy, xx = x + dx;
        if (yy >= 0 && yy < HM_H && xx >= 0 && xx < HM_W)
          m = fmaxf(m, ws_hm[yy * HM_W + xx]);
      }
    v = (c == m) ? c : 0.f;
    idx = p;
  }
  sv[t * 4] = v; si[t * 4] = idx;
  #pragma unroll
  for (int k = 1; k < 4; ++k) { sv[t * 4 + k] = -1.f; si[t * 4 + k] = INT_MAX; }
  __syncthreads();
  top4_tree<256>(sv, si, t);
  if (t == 0) {
    #pragma unroll
    for (int k = 0; k < 4; ++k) { candv[b * 4 + k] = sv[k]; candi[b * 4 + k] = si[k]; }
  }
}

// ------------------------------------------------------------------
// K2b: final merge of 128 x 4 candidates
// ------------------------------------------------------------------
__global__ void k_topk_final(const float* __restrict__ candv, const int* __restrict__ candi,
                             int* __restrict__ ws_inds, float* __restrict__ d_out) {
  __shared__ float sv[128 * 4];
  __shared__ int   si[128 * 4];
  int t = threadIdx.x;   // 128
  #pragma unroll
  for (int k = 0; k < 4; ++k) { sv[t * 4 + k] = candv[t * 4 + k]; si[t * 4 + k] = candi[t * 4 + k]; }
  __syncthreads();
  top4_tree<128>(sv, si, t);
  if (t == 0) {
    #pragma unroll
    for (int k = 0; k < 4; ++k) {
      d_out[k]     = sv[k];
      d_out[4 + k] = (float)si[k];
      ws_inds[k]   = si[k];
    }
  }
}

// ------------------------------------------------------------------
// K3: gen_params for the 4 winners
// ------------------------------------------------------------------
__global__ void k_gen(const float* __restrict__ out1, const float* __restrict__ params_w,
                      const float* __restrict__ params_b, const int* __restrict__ ws_inds,
                      float* __restrict__ ws_gp) {
  __shared__ float col[C_IN];
  int i = blockIdx.x;
  int p = ws_inds[i];
  col[threadIdx.x] = out1[threadIdx.x * HM_N + p];
  __syncthreads();
  int j = threadIdx.x;
  if (j < NP) {
    float s = params_b[j];
    #pragma unroll 8
    for (int c = 0; c < C_IN; ++c) s += params_w[j * C_IN + c] * col[c];
    ws_gp[i * NP + j] = s;
  }
}

// ------------------------------------------------------------------
// K4: MFMA implicit-GEMM conv, double-buffered LDS staging.
// Tile 8x32 pixels; stage 10 rows x 40 x-cols (x-pairs, even-aligned) x 32 c.
// ------------------------------------------------------------------
#define CS 40      // LDS c-stride per pixel (ushorts); keeps b128 16B alignment
#define RP 36      // row pitch in pixels (xloc 0..35 stored)
#define BUFU 14400 // ushorts per staging buffer (10*36*40)

__global__ __launch_bounds__(256, 2) void k_conv_mfma(
    const float* __restrict__ out0, const unsigned short* __restrict__ wt,
    const float* __restrict__ mb_b, const float* __restrict__ ws_gp,
    float* __restrict__ d_out) {
  __shared__ unsigned short smem[2 * BUFU];   // 57600 B

  int tid  = threadIdx.x;
  int lane = tid & 63;
  int w    = tid >> 6;
  int n15  = lane & 15;
  int kq   = lane >> 4;
  int gx0 = blockIdx.x * 32, gy0 = blockIdx.y * 8;

  // --- precompute staging descriptors (25 x-pair units/thread) ---
  int goff[25], lofs[25];
  unsigned int mld = 0, mst0 = 0, mst1 = 0;
  #pragma unroll
  for (int i = 0; i < 25; ++i) {
    int u = tid + 256 * i;          // 0..6399
    int c   = u / 200;
    int rem = u - c * 200;
    int row = rem / 20;
    int q   = rem - row * 20;
    int iy  = gy0 + row - 1;
    int ixe = gx0 + 2 * q - 2;      // even -> 8B-aligned pair
    bool vld = (iy >= 0) && (iy < MH) && (ixe >= 0) && (ixe < MW);
    goff[i] = vld ? (c * MN + iy * MW + ixe) : 0;
    if (vld) mld |= (1u << i);
    int x0 = 2 * q - 1;             // xloc of elem0
    lofs[i] = (row * RP + x0) * CS + c;
    if (x0 >= 0 && x0 < RP)     mst0 |= (1u << i);
    if (x0 + 1 < RP)            mst1 |= (1u << i);
  }

  // A-frag geometry
  int rrow[4], xbas[4];
  #pragma unroll
  for (int i = 0; i < 4; ++i) {
    int mt = w * 4 + i;
    rrow[i] = mt >> 1;
    xbas[i] = (mt & 1) * 16 + n15;
  }

  // --- prologue: stage ch-group 0 into buf0 ---
  {
    float2 d[25];
    #pragma unroll
    for (int i = 0; i < 25; ++i) d[i] = *(const float2*)(out0 + goff[i]);
    #pragma unroll
    for (int i = 0; i < 25; ++i) {
      bool vl = (mld >> i) & 1;
      float a = vl ? d[i].x : 0.f, bb = vl ? d[i].y : 0.f;
      if ((mst0 >> i) & 1) smem[lofs[i]]      = f2bf(a);
      if ((mst1 >> i) & 1) smem[lofs[i] + CS] = f2bf(bb);
    }
  }
  __syncthreads();

  f32x4 acc[4][4];
  #pragma unroll
  for (int i = 0; i < 4; ++i)
    #pragma unroll
    for (int nt = 0; nt < 4; ++nt)
      acc[i][nt] = (f32x4){0.f, 0.f, 0.f, 0.f};

  #pragma unroll 1
  for (int g = 0; g < 8; ++g) {
    const unsigned short* cur = smem + (g & 1) * BUFU;
    unsigned short*       nxt = smem + ((g + 1) & 1) * BUFU;
    const float*          src = out0 + (g + 1) * (32 * MN);
    float2 d[25];

    // half A: prefetch 13 pairs, MFMA taps 0..3, write half A
    if (g < 7) {
      #pragma unroll
      for (int i = 0; i < 13; ++i) d[i] = *(const float2*)(src + goff[i]);
    }
    #pragma unroll
    for (int t = 0; t < 4; ++t) {
      int ty = t / 3, tx = t - ty * 3;
      const unsigned short* wb = wt + (g * 9 + t) * 2048 + lane * 8;
      bf16x8 bfrag[4], afrag[4];
      #pragma unroll
      for (int nt = 0; nt < 4; ++nt) bfrag[nt] = *(const bf16x8*)(wb + nt * 512);
      #pragma unroll
      for (int i = 0; i < 4; ++i)
        afrag[i] = *(const bf16x8*)&cur[((rrow[i] + ty) * RP + xbas[i] + tx) * CS + kq * 8];
      #pragma unroll
      for (int i = 0; i < 4; ++i)
        #pragma unroll
        for (int nt = 0; nt < 4; ++nt)
          acc[i][nt] = __builtin_amdgcn_mfma_f32_16x16x32_bf16(afrag[i], bfrag[nt], acc[i][nt], 0, 0, 0);
    }
    if (g < 7) {
      #pragma unroll
      for (int i = 0; i < 13; ++i) {
        bool vl = (mld >> i) & 1;
        float a = vl ? d[i].x : 0.f, bb = vl ? d[i].y : 0.f;
        if ((mst0 >> i) & 1) nxt[lofs[i]]      = f2bf(a);
        if ((mst1 >> i) & 1) nxt[lofs[i] + CS] = f2bf(bb);
      }
      // half B: prefetch remaining 12 pairs
      #pragma unroll
      for (int i = 13; i < 25; ++i) d[i] = *(const float2*)(src + goff[i]);
    }
    #pragma unroll
    for (int t = 4; t < 9; ++t) {
      int ty = t / 3, tx = t - ty * 3;
      const unsigned short* wb = wt + (g * 9 + t) * 2048 + lane * 8;
      bf16x8 bfrag[4], afrag[4];
      #pragma unroll
      for (int nt = 0; nt < 4; ++nt) bfrag[nt] = *(const bf16x8*)(wb + nt * 512);
      #pragma unroll
      for (int i = 0; i < 4; ++i)
        afrag[i] = *(const bf16x8*)&cur[((rrow[i] + ty) * RP + xbas[i] + tx) * CS + kq * 8];
      #pragma unroll
      for (int i = 0; i < 4; ++i)
        #pragma unroll
        for (int nt = 0; nt < 4; ++nt)
          acc[i][nt] = __builtin_amdgcn_mfma_f32_16x16x32_bf16(afrag[i], bfrag[nt], acc[i][nt], 0, 0, 0);
    }
    if (g < 7) {
      #pragma unroll
      for (int i = 13; i < 25; ++i) {
        bool vl = (mld >> i) & 1;
        float a = vl ? d[i].x : 0.f, bb = vl ? d[i].y : 0.f;
        if ((mst0 >> i) & 1) nxt[lofs[i]]      = f2bf(a);
        if ((mst1 >> i) & 1) nxt[lofs[i] + CS] = f2bf(bb);
      }
    }
    __syncthreads();
  }

  // --- epilogue: bias+relu, acc -> LDS [pixel][channel] bf16 ---
  #define ES 66
  float bias[4];
  #pragma unroll
  for (int nt = 0; nt < 4; ++nt) bias[nt] = mb_b[nt * 16 + n15];
  #pragma unroll
  for (int i = 0; i < 4; ++i) {
    int mt = w * 4 + i;
    int pbase = (mt >> 1) * 32 + (mt & 1) * 16;
    #pragma unroll
    for (int nt = 0; nt < 4; ++nt)
      #pragma unroll
      for (int reg = 0; reg < 4; ++reg) {
        float vv = fmaxf(acc[i][nt][reg] + bias[nt], 0.f);
        smem[(pbase + kq * 4 + reg) * ES + nt * 16 + n15] = f2bf(vv);
      }
  }
  __syncthreads();

  // dynamic heads: thread tid owns pixel tid
  int r = tid >> 5, xcol = tid & 31;
  int gy = gy0 + r, gx = gx0 + xcol;
  float xc = -1.f + (2.f / 479.f) * (float)gx;
  float yc = -1.f + (2.f / 271.f) * (float)gy;
  float mres[4] = {0.f, 0.f, 0.f, 0.f};
  float rres[4] = {0.f, 0.f, 0.f, 0.f};
  #pragma unroll 8
  for (int o = 0; o < MB; ++o) {
    float v = b2f(smem[tid * ES + o]);
    #pragma unroll
    for (int i = 0; i < 4; ++i) {
      mres[i] += ws_gp[i * NP + o] * v;
      rres[i] += ws_gp[i * NP + 67 + o] * v;
    }
  }
  int pix = gy * MW + gx;
  #pragma unroll
  for (int i = 0; i < 4; ++i) {
    const float* g = ws_gp + i * NP;
    d_out[MASK_OFF + i * MN + pix] = mres[i] + g[66]  + g[64]  * xc + g[65]  * yc;
    d_out[REG_OFF  + i * MN + pix] = rres[i] + g[133] + g[131] * xc + g[132] * yc;
  }
}

// ------------------------------------------------------------------
// K5: feat_range MLP
// ------------------------------------------------------------------
__global__ void k_mlp(const float* __restrict__ masks0, const float* __restrict__ w1,
                      const float* __restrict__ b1, const float* __restrict__ w2,
                      const float* __restrict__ b2, float* __restrict__ d_out) {
  int blk = blockIdx.x;          // i*480 + w
  int i = blk / MW;
  int w = blk - i * MW;
  int k = threadIdx.x;           // 0..63
  const float* mcol = masks0 + i * MN + w;
  float s = b1[k];
  for (int h = 0; h < MH; ++h) s += mcol[h * MW] * w1[h * HID + k];
  s = fmaxf(s, 0.f);
  float o0 = s * w2[k * 2 + 0];
  float o1 = s * w2[k * 2 + 1];
  #pragma unroll
  for (int off = 32; off >= 1; off >>= 1) {
    o0 += __shfl_down(o0, off);
    o1 += __shfl_down(o1, off);
  }
  if (k == 0) {
    d_out[FEAT_OFF + blk * 2 + 0] = o0 + b2[0];
    d_out[FEAT_OFF + blk * 2 + 1] = o1 + b2[1];
  }
}

// ------------------------------------------------------------------
extern "C" void kernel_launch(void* const* d_in, const int* in_sizes, int n_in,
                              void* d_out, int out_size, void* d_ws, size_t ws_size,
                              hipStream_t stream) {
  const float* out0     = (const float*)d_in[0];
  const float* out1     = (const float*)d_in[1];
  const float* hm_w     = (const float*)d_in[2];
  const float* hm_b     = (const float*)d_in[3];
  const float* params_w = (const float*)d_in[4];
  const float* params_b = (const float*)d_in[5];
  const float* mb_w     = (const float*)d_in[6];
  const float* mb_b     = (const float*)d_in[7];
  const float* mlp_w1   = (const float*)d_in[8];
  const float* mlp_b1   = (const float*)d_in[9];
  const float* mlp_w2   = (const float*)d_in[10];
  const float* mlp_b2   = (const float*)d_in[11];

  float* ws      = (float*)d_ws;
  float* ws_hm   = ws + WS_HM;
  float* candv   = ws + WS_CV;
  int*   candi   = (int*)(ws + WS_CI);
  float* ws_gp   = ws + WS_GP;
  int*   ws_inds = (int*)(ws + WS_INDS);
  unsigned short* ws_wt = (unsigned short*)(ws + WS_WT_F);
  float* out     = (float*)d_out;

  k_wprep<<<576, 256, 0, stream>>>(mb_w, ws_wt);
  k_hm  <<<510, 256, 0, stream>>>(out1, hm_w, hm_b, ws_hm);
  k_nms_top<<<128, 256, 0, stream>>>(ws_hm, candv, candi);
  k_topk_final<<<1, 128, 0, stream>>>(candv, candi, ws_inds, out);
  k_gen <<<NI, 256, 0, stream>>>(out1, params_w, params_b, ws_inds, ws_gp);
  dim3 gconv(MW / 32, MH / 8);   // 15 x 34
  k_conv_mfma<<<gconv, 256, 0, stream>>>(out0, ws_wt, mb_b, ws_gp, out);
  k_mlp <<<NI * MW, 64, 0, stream>>>(out + MASK_OFF, mlp_w1, mlp_b1, mlp_w2, mlp_b2, out);
}